// Round 2
// baseline (1129.874 us; speedup 1.0000x reference)
//
#include <hip/hip_runtime.h>
#include <stdint.h>

#pragma clang fp contract(off)   // match numpy: no FMA fusion in decode/IoU math

static constexpr int TOPK  = 5000;
static constexpr int KEEPK = 750;
static constexpr int MPAD  = 65536;   // >= N (33600), power of 2
static constexpr int KPAD  = 8192;    // >= TOPK, power of 2
static constexpr int NBLK  = (TOPK + 63) / 64;   // 79
static constexpr int KROW  = NBLK * 64;          // 5056 (padded mask row)
static constexpr float TH  = 0.3f;    // strict '>' everywhere (f32 weak-typed 0.3)

__device__ __forceinline__ uint32_t key_of(float f) {
  uint32_t u = __float_as_uint(f);
  u = (u & 0x80000000u) ? ~u : (u | 0x80000000u);  // ascending-ordered uint
  return ~u;                                        // ascending key == descending float
}
__device__ __forceinline__ float val_of(uint32_t key) {
  uint32_t u = ~key;
  return (u & 0x80000000u) ? __uint_as_float(u ^ 0x80000000u) : __uint_as_float(~u);
}

// ---------------- stage 1: composite keys (score desc, index asc) ----------------
__global__ void build_keys(const float* __restrict__ cls, const float* __restrict__ obj,
                           uint64_t* __restrict__ keys, int N) {
  int b = blockIdx.y;
  int i = blockIdx.x * blockDim.x + threadIdx.x;
  if (i >= MPAD) return;
  uint64_t c = ~0ull;
  if (i < N) {
    size_t o = (size_t)b * N + i;
    float s = sqrtf(cls[o] * obj[o]);          // mul+sqrt: bit-exact vs np
    float m = (s > TH) ? s : -1.0f;            // strict > (jax weak-typed f32 0.3)
    c = ((uint64_t)key_of(m) << 32) | (uint32_t)i;
  }
  keys[(size_t)b * MPAD + i] = c;
}

// ---------------- bitonic sort (ascending) over MPAD per batch ----------------
__global__ __launch_bounds__(1024) void bitonic_local_full(uint64_t* __restrict__ keys) {
  __shared__ uint64_t sh[8192];
  int base = blockIdx.x * 8192;
  uint64_t* a = keys + (size_t)blockIdx.y * MPAD + base;
  for (int t = threadIdx.x; t < 8192; t += 1024) sh[t] = a[t];
  __syncthreads();
  for (int k = 2; k <= 8192; k <<= 1) {
    for (int j = k >> 1; j > 0; j >>= 1) {
      for (int t = threadIdx.x; t < 4096; t += 1024) {
        int i = ((t & ~(j - 1)) << 1) | (t & (j - 1));
        int l = i | j;
        bool asc = (((base + i) & k) == 0);
        uint64_t x = sh[i], y = sh[l];
        if ((x > y) == asc) { sh[i] = y; sh[l] = x; }
      }
      __syncthreads();
    }
  }
  for (int t = threadIdx.x; t < 8192; t += 1024) a[t] = sh[t];
}

__global__ void bitonic_global_pass(uint64_t* __restrict__ keys, int k, int j) {
  int b = blockIdx.y;
  int t = blockIdx.x * blockDim.x + threadIdx.x;  // t < MPAD/2
  uint64_t* a = keys + (size_t)b * MPAD;
  int i = ((t & ~(j - 1)) << 1) | (t & (j - 1));
  int l = i | j;
  bool asc = ((i & k) == 0);
  uint64_t x = a[i], y = a[l];
  if ((x > y) == asc) { a[i] = y; a[l] = x; }
}

__global__ __launch_bounds__(1024) void bitonic_local_finish(uint64_t* __restrict__ keys, int k) {
  __shared__ uint64_t sh[8192];
  int base = blockIdx.x * 8192;
  uint64_t* a = keys + (size_t)blockIdx.y * MPAD + base;
  for (int t = threadIdx.x; t < 8192; t += 1024) sh[t] = a[t];
  __syncthreads();
  for (int j = 4096; j > 0; j >>= 1) {
    for (int t = threadIdx.x; t < 4096; t += 1024) {
      int i = ((t & ~(j - 1)) << 1) | (t & (j - 1));
      int l = i | j;
      bool asc = (((base + i) & k) == 0);
      uint64_t x = sh[i], y = sh[l];
      if ((x > y) == asc) { sh[i] = y; sh[l] = x; }
    }
    __syncthreads();
  }
  for (int t = threadIdx.x; t < 8192; t += 1024) a[t] = sh[t];
}

// ---------------- stage 2: gather top-5000, decode boxes+kps ----------------
__global__ void gather_decode(const uint64_t* __restrict__ keys,
                              const float* __restrict__ bbox, const float* __restrict__ kps,
                              const float* __restrict__ priors,
                              float* __restrict__ dets, float* __restrict__ tscore, int N) {
  int b = blockIdx.y;
  int r = blockIdx.x * blockDim.x + threadIdx.x;
  if (r >= TOPK) return;
  uint64_t c = keys[(size_t)b * MPAD + r];
  uint32_t idx = (uint32_t)c;
  float score = val_of((uint32_t)(c >> 32));
  float4 pr = ((const float4*)priors)[idx];
  const float* bb = bbox + ((size_t)b * N + idx) * 4;
  float cx = pr.x + bb[0] * pr.z;
  float cy = pr.y + bb[1] * pr.w;
  float w = pr.z * expf(bb[2]);
  float h = pr.w * expf(bb[3]);
  float x1 = cx - w * 0.5f, y1 = cy - h * 0.5f;
  float* d = dets + ((size_t)b * TOPK + r) * 16;
  d[0] = x1; d[1] = y1; d[2] = x1 + w; d[3] = y1 + h;
  const float* kp = kps + ((size_t)b * N + idx) * 10;
#pragma unroll
  for (int q = 0; q < 5; ++q) {
    d[4 + 2 * q] = pr.x + kp[2 * q] * pr.z;
    d[5 + 2 * q] = pr.y + kp[2 * q + 1] * pr.w;
  }
  d[14] = score;
  tscore[(size_t)b * TOPK + r] = score;
}

// ---------------- stage 3: NMS suppression bitmask (upper triangle) ----------------
__global__ __launch_bounds__(64) void nms_mask(const float* __restrict__ dets,
                                               uint64_t* __restrict__ mask) {
  int ib = blockIdx.x, jb = blockIdx.y, b = blockIdx.z;
  if (jb < ib) return;
  __shared__ float4 jbox[64];
  int t = threadIdx.x;
  int j0 = jb * 64;
  {
    int j = j0 + t;
    if (j < TOPK) {
      const float* dj = dets + ((size_t)b * TOPK + j) * 16;
      jbox[t] = make_float4(dj[0], dj[1], dj[2], dj[3]);
    } else jbox[t] = make_float4(0.f, 0.f, 0.f, 0.f);
  }
  __syncthreads();
  int i = ib * 64 + t;
  uint64_t bits = 0;
  if (i < TOPK) {
    const float* di = dets + ((size_t)b * TOPK + i) * 16;
    float ix1 = di[0], iy1 = di[1], ix2 = di[2], iy2 = di[3];
    float iar = fmaxf(ix2 - ix1, 0.f) * fmaxf(iy2 - iy1, 0.f);
    int jmax = min(64, TOPK - j0);
    for (int u = 0; u < jmax; ++u) {
      int j = j0 + u;
      if (j <= i) continue;
      float4 bx = jbox[u];
      float xx1 = fmaxf(ix1, bx.x), yy1 = fmaxf(iy1, bx.y);
      float xx2 = fminf(ix2, bx.z), yy2 = fminf(iy2, bx.w);
      float ww = fmaxf(xx2 - xx1, 0.f), hh = fmaxf(yy2 - yy1, 0.f);
      float inter = ww * hh;
      float jar = fmaxf(bx.z - bx.x, 0.f) * fmaxf(bx.w - bx.y, 0.f);
      float iou = inter / (iar + jar - inter + 1e-12f);
      if (iou > TH) bits |= (1ull << u);       // strict > (f32 0.3)
    }
  }
  mask[((size_t)b * NBLK + jb) * KROW + (size_t)(ib * 64 + t)] = bits;
}

// ---------------- stage 4: greedy scan (chunked, 1 block/batch) ----------------
__global__ __launch_bounds__(128) void nms_scan(const uint64_t* __restrict__ mask,
                                                const float* __restrict__ tscore,
                                                uint8_t* __restrict__ keep) {
  int b = blockIdx.x;
  __shared__ uint64_t remv[NBLK];
  __shared__ uint64_t cmask[64];
  __shared__ uint64_t aliveword;
  int tid = threadIdx.x;
  for (int t = tid; t < NBLK; t += blockDim.x) remv[t] = 0;
  const uint64_t* mb = mask + (size_t)b * NBLK * KROW;
  const float* sb = tscore + (size_t)b * TOPK;
  __syncthreads();
  for (int bi = 0; bi < NBLK; ++bi) {
    int i0 = bi * 64;
    if (tid < 64) cmask[tid] = mb[(size_t)bi * KROW + i0 + tid];
    __syncthreads();
    if (tid == 0) {
      uint64_t w = remv[bi], alive = 0;
      int lim = min(64, TOPK - i0);
      for (int t = 0; t < lim; ++t) {
        if (!((w >> t) & 1ull) && sb[i0 + t] > TH) {
          alive |= 1ull << t;
          w |= cmask[t];
        }
      }
      remv[bi] = w;
      aliveword = alive;
    }
    __syncthreads();
    uint64_t a0 = aliveword;
    if (a0) {
      for (int jb = bi + 1 + tid; jb < NBLK; jb += blockDim.x) {
        uint64_t acc = remv[jb];
        const uint64_t* row = mb + (size_t)jb * KROW + i0;
#pragma unroll 64
        for (int u = 0; u < 64; ++u) {
          uint64_t m = row[u];
          acc |= (((a0 >> u) & 1ull) ? m : 0ull);
        }
        remv[jb] = acc;
      }
    }
    __syncthreads();
  }
  for (int i = tid; i < TOPK; i += blockDim.x)
    keep[(size_t)b * TOPK + i] =
        (sb[i] > TH && !((remv[i >> 6] >> (i & 63)) & 1ull)) ? 1 : 0;
}

// ---------------- stage 5: final top-750 + emit ----------------
__global__ __launch_bounds__(1024) void final_topk(const float* __restrict__ tscore,
                                                   const uint8_t* __restrict__ keep,
                                                   const float* __restrict__ dets,
                                                   float* __restrict__ out, int B) {
  int b = blockIdx.x;
  __shared__ uint64_t sh[KPAD];
  for (int t = threadIdx.x; t < KPAD; t += 1024) {
    uint64_t c = ~0ull;
    if (t < TOPK) {
      float s = keep[(size_t)b * TOPK + t] ? tscore[(size_t)b * TOPK + t] : -1.0f;
      c = ((uint64_t)key_of(s) << 32) | (uint32_t)t;   // -1 ties -> index asc (jax stable)
    }
    sh[t] = c;
  }
  __syncthreads();
  for (int k = 2; k <= KPAD; k <<= 1) {
    for (int j = k >> 1; j > 0; j >>= 1) {
      for (int t = threadIdx.x; t < KPAD / 2; t += 1024) {
        int i = ((t & ~(j - 1)) << 1) | (t & (j - 1));
        int l = i | j;
        bool asc = ((i & k) == 0);
        uint64_t x = sh[i], y = sh[l];
        if ((x > y) == asc) { sh[i] = y; sh[l] = x; }
      }
      __syncthreads();
    }
  }
  // dets (score col = pre-suppression top_scores, exactly like reference)
  for (int e = threadIdx.x; e < KEEPK * 15; e += 1024) {
    int q = e / 15, col = e - q * 15;
    uint32_t r = (uint32_t)sh[q];
    out[((size_t)b * KEEPK + q) * 15 + col] = dets[((size_t)b * TOPK + r) * 16 + col];
  }
  float* ov = out + (size_t)B * KEEPK * 15;
  for (int q = threadIdx.x; q < KEEPK; q += 1024) {
    float fs = val_of((uint32_t)(sh[q] >> 32));
    ov[(size_t)b * KEEPK + q] = (fs > TH) ? 1.0f : 0.0f;
  }
}

extern "C" void kernel_launch(void* const* d_in, const int* in_sizes, int n_in,
                              void* d_out, int out_size, void* d_ws, size_t ws_size,
                              hipStream_t stream) {
  const float* cls    = (const float*)d_in[0];
  const float* obj    = (const float*)d_in[1];
  const float* bbox   = (const float*)d_in[2];
  const float* kps    = (const float*)d_in[3];
  const float* priors = (const float*)d_in[4];
  int N = in_sizes[4] / 4;
  int B = in_sizes[0] / N;
  if (N > MPAD) return;

  char* ws = (char*)d_ws;
  size_t off = 0;
  auto alloc = [&](size_t bytes) -> void* {
    void* p = ws + off;
    off += (bytes + 255) & ~(size_t)255;
    return p;
  };
  uint64_t* keys1  = (uint64_t*)alloc((size_t)B * MPAD * 8);
  float*    dets   = (float*)   alloc((size_t)B * TOPK * 16 * 4);
  float*    tscore = (float*)   alloc((size_t)B * TOPK * 4);
  uint64_t* mask   = (uint64_t*)alloc((size_t)B * NBLK * KROW * 8);
  uint8_t*  keep   = (uint8_t*) alloc((size_t)B * TOPK);
  if (off > ws_size) return;  // fail visibly rather than corrupt

  build_keys<<<dim3((MPAD + 255) / 256, B), 256, 0, stream>>>(cls, obj, keys1, N);
  bitonic_local_full<<<dim3(MPAD / 8192, B), 1024, 0, stream>>>(keys1);
  for (int k = 16384; k <= MPAD; k <<= 1) {
    for (int j = k >> 1; j >= 8192; j >>= 1)
      bitonic_global_pass<<<dim3(MPAD / 2 / 256, B), 256, 0, stream>>>(keys1, k, j);
    bitonic_local_finish<<<dim3(MPAD / 8192, B), 1024, 0, stream>>>(keys1, k);
  }
  gather_decode<<<dim3((TOPK + 255) / 256, B), 256, 0, stream>>>(keys1, bbox, kps, priors,
                                                                 dets, tscore, N);
  nms_mask<<<dim3(NBLK, NBLK, B), 64, 0, stream>>>(dets, mask);
  nms_scan<<<B, 128, 0, stream>>>(mask, tscore, keep);
  final_topk<<<B, 1024, 0, stream>>>(tscore, keep, dets, (float*)d_out, B);
}